// Round 2
// baseline (486.143 us; speedup 1.0000x reference)
//
#include <hip/hip_runtime.h>
#include <hip/hip_bf16.h>
#include <stdint.h>

#define NR 8192
#define FD 512
#define BM 64     // k_attn rows per band

typedef __attribute__((ext_vector_type(8))) short s8v;   // 8 bf16 (4 VGPRs) - MFMA A/B frag
typedef __attribute__((ext_vector_type(4))) float f32x4; // MFMA C/D frag

static __device__ __forceinline__ short bf16_rtne(float x) {
    union { float f; uint32_t u; } v; v.f = x;
    uint32_t r = (v.u + 0x7FFFu + ((v.u >> 16) & 1u)) >> 16;
    return (short)r;
}
static __device__ __forceinline__ float bf16_to_f32(short s) {
    union { uint32_t u; float f; } v; v.u = ((uint32_t)(uint16_t)s) << 16;
    return v.f;
}

// ---------------- K0: fused fp32->bf16 convert (inp) + W1 transpose --------
__global__ void k_prep(const float* __restrict__ in, short* __restrict__ out,
                       const float* __restrict__ W1, short* __restrict__ W1T) {
    int b = blockIdx.x;
    if (b < 4096) {
        int i = b * 256 + threadIdx.x;               // one float4 per thread
        float4 v = ((const float4*)in)[i];
        short4 s;
        s.x = bf16_rtne(v.x); s.y = bf16_rtne(v.y);
        s.z = bf16_rtne(v.z); s.w = bf16_rtne(v.w);
        ((short4*)out)[i] = s;
    } else {
        int i = (b - 4096) * 256 + threadIdx.x;      // 512*512
        int k = i & 511, n = i >> 9;
        W1T[(size_t)n * 512 + k] = bf16_rtne(W1[(size_t)k * 512 + n]);
    }
}

// ---------------- K1: h = inp @ W1 + b1 ; writes h AND ht3 ----------------
// ht3 layout per 32-j tile jt: [wave=c/64][nt=(c%64)/16][qg=jrow/8][cm=c%16][jr=jrow%8]
// -> every k_attn B-frag load is a fully-coalesced lane-linear 1KB dwordx4.
__launch_bounds__(256)
__global__ void k_gemm_h(const short* __restrict__ A,   // inp bf16 [8192][512]
                         const short* __restrict__ BT,  // W1T bf16 [512][512]
                         const float* __restrict__ b1,
                         short* __restrict__ H,         // bf16 [8192][512]
                         short* __restrict__ HT3)       // bf16 [256][16384]
{
    const int lane = threadIdx.x & 63;
    const int wn   = threadIdx.x >> 6;     // 0..3
    const int m    = lane & 15;
    const int q    = lane >> 4;
    const int r0   = blockIdx.x * 32;
    const int c0   = blockIdx.y * 128 + wn * 32;

    f32x4 acc[2][2] = {};
#pragma unroll 1
    for (int k0 = 0; k0 < 512; k0 += 32) {
        s8v a[2], b[2];
#pragma unroll
        for (int rt = 0; rt < 2; ++rt)
            a[rt] = *(const s8v*)(A + (size_t)(r0 + rt * 16 + m) * 512 + k0 + q * 8);
#pragma unroll
        for (int nt = 0; nt < 2; ++nt)
            b[nt] = *(const s8v*)(BT + (size_t)(c0 + nt * 16 + m) * 512 + k0 + q * 8);
#pragma unroll
        for (int rt = 0; rt < 2; ++rt)
#pragma unroll
            for (int nt = 0; nt < 2; ++nt)
                acc[rt][nt] = __builtin_amdgcn_mfma_f32_16x16x32_bf16(a[rt], b[nt], acc[rt][nt], 0, 0, 0);
    }
    float b1v[2];
#pragma unroll
    for (int nt = 0; nt < 2; ++nt) b1v[nt] = b1[c0 + nt * 16 + m];

#pragma unroll
    for (int rt = 0; rt < 2; ++rt)
#pragma unroll
        for (int nt = 0; nt < 2; ++nt) {
            int col = c0 + nt * 16 + m;
            short4 hp;
#pragma unroll
            for (int r = 0; r < 4; ++r) {
                int row = r0 + rt * 16 + q * 4 + r;
                short hv = bf16_rtne(acc[rt][nt][r] + b1v[nt]);
                H[(size_t)row * 512 + col] = hv;
                ((short*)&hp)[r] = hv;
            }
            size_t off = (size_t)blockIdx.x * 16384
                       + (size_t)(blockIdx.y * 2 + (wn >> 1)) * 2048
                       + (size_t)((wn * 2 + nt) & 3) * 512
                       + (rt * 2 + (q >> 1)) * 128
                       + m * 8 + (q & 1) * 4;
            *(short4*)(HT3 + off) = hp;
        }
}

// ---------------- K3: f1 = h@a1, f2s = h@a2 + b2 ----------------
__global__ void k_f1f2(const short* __restrict__ H, const float* __restrict__ a1,
                       const float* __restrict__ a2, const float* __restrict__ b2,
                       float* __restrict__ f1, float* __restrict__ f2s)
{
    const int lane = threadIdx.x & 63;
    const int row  = blockIdx.x * 4 + (threadIdx.x >> 6);
    s8v hv = *(const s8v*)(H + (size_t)row * 512 + lane * 8);
    float4 a1l = ((const float4*)(a1 + lane * 8))[0];
    float4 a1h = ((const float4*)(a1 + lane * 8))[1];
    float4 a2l = ((const float4*)(a2 + lane * 8))[0];
    float4 a2h = ((const float4*)(a2 + lane * 8))[1];
    float hf[8];
#pragma unroll
    for (int i = 0; i < 8; ++i) hf[i] = bf16_to_f32(hv[i]);
    float s1 = hf[0] * a1l.x + hf[1] * a1l.y + hf[2] * a1l.z + hf[3] * a1l.w
             + hf[4] * a1h.x + hf[5] * a1h.y + hf[6] * a1h.z + hf[7] * a1h.w;
    float s2 = hf[0] * a2l.x + hf[1] * a2l.y + hf[2] * a2l.z + hf[3] * a2l.w
             + hf[4] * a2h.x + hf[5] * a2h.y + hf[6] * a2h.z + hf[7] * a2h.w;
#pragma unroll
    for (int o = 32; o > 0; o >>= 1) {
        s1 += __shfl_xor(s1, o);
        s2 += __shfl_xor(s2, o);
    }
    if (lane == 0) {
        f1[row]  = s1;
        f2s[row] = s2 + b2[0];
    }
}

// ---------------- K4: fused masked-softmax attention @ h (partials) --------
// grid 256 = 128 bands x 2 j-splits, 512 thr / 8 waves.
// adj is read directly (no prepack) and COMPRESSED to a per-unit byte mask at
// load time (kk=0..3, in the MFMA shadow) — staged state per unit is 1 mask
// VGPR + 8 f2 floats instead of 8 raw ints + 8 floats (-28 VGPR vs round 0).
// Masks/f2 are consumed 3 kt later at kk=3..6 (~930 cyc distance -> covers
// HBM latency). B-frags: depth-2 REGISTER prefetch from ht3 (coalesced 1KB
// dwordx4). Weight tile: LDS dbuf (64 KB), one barrier per 256-j chunk.
__launch_bounds__(512, 2)
__global__ void k_attn(const int* __restrict__ adj,    // [8192][8192] int 0/1
                       const short* __restrict__ HT3,  // [256][16384]
                       const float* __restrict__ f1,
                       const float* __restrict__ f2s,
                       float* __restrict__ nump,       // [2][8192][512]
                       float* __restrict__ denomp)     // [2][8192]
{
    __shared__ __align__(16) short wt[2][BM * 256];    // 2 x 32 KB

    const int t    = threadIdx.x;
    const int lane = t & 63;
    const int w    = t >> 6;          // 0..7 col group (64 cols)
    const int m    = lane & 15;
    const int q    = lane >> 4;

    const int js   = blockIdx.x & 1;
    const int band = blockIdx.x >> 1; // 0..127
    const int r0   = band * BM;
    const int jb0  = js * 4096;
    const int jt0  = js * 128;        // first 32-j tile index

    const int prow = t >> 3;          // 0..63
    const int jg   = t & 7;

    const float f1v = f1[r0 + prow];
    const int* adjrow = adj + (size_t)(r0 + prow) * NR + jb0;
    const float* f2base = f2s + jb0;

    f32x4 acc[4][4] = {};
    float dsum = 0.f;

#define GAT_BLOAD(DST, KT)                                                     \
    {                                                                          \
        const short* s_ = HT3 + (size_t)(jt0 + (KT)) * 16384 + w * 2048        \
                        + q * 128 + m * 8;                                     \
        DST[0] = *(const s8v*)(s_);                                            \
        DST[1] = *(const s8v*)(s_ + 512);                                      \
        DST[2] = *(const s8v*)(s_ + 1024);                                     \
        DST[3] = *(const s8v*)(s_ + 1536);                                     \
    }

// load 8 adj ints for unit U and compress to an 8-bit mask (bit jj = col jj)
#define GAT_MLOAD(DST, AP, U)                                                  \
    {                                                                          \
        uint4 ma_ = *(const uint4*)((AP) + (U) * 8);                           \
        uint4 mb_ = *(const uint4*)((AP) + (U) * 8 + 4);                       \
        DST = ((int)ma_.x > 0 ? 1u : 0u)  | ((int)ma_.y > 0 ? 2u : 0u)         \
            | ((int)ma_.z > 0 ? 4u : 0u)  | ((int)ma_.w > 0 ? 8u : 0u)         \
            | ((int)mb_.x > 0 ? 16u : 0u) | ((int)mb_.y > 0 ? 32u : 0u)        \
            | ((int)mb_.z > 0 ? 64u : 0u) | ((int)mb_.w > 0 ? 128u : 0u);      \
    }

// one unit (8 weights) of row prow into wt[P]; BYTE = 8-bit mask, FA/FB float4
#define GAT_WUNIT(U, BYTE, FA, FB, P)                                          \
    {                                                                          \
        s8v wv_;                                                               \
        const float* ff_ = (const float*)&(FA);                                \
        _Pragma("unroll")                                                      \
        for (int jj = 0; jj < 4; ++jj) {                                       \
            float s_ = f1v + ff_[jj];                                          \
            float e_ = __expf(fmaxf(s_, 0.2f * s_));                           \
            float x_ = (((BYTE) >> jj) & 1u) ? e_ : 0.f;                       \
            dsum += x_; wv_[jj] = bf16_rtne(x_);                               \
        }                                                                      \
        const float* fg_ = (const float*)&(FB);                               \
        _Pragma("unroll")                                                      \
        for (int jj = 0; jj < 4; ++jj) {                                       \
            float s_ = f1v + fg_[jj];                                          \
            float e_ = __expf(fmaxf(s_, 0.2f * s_));                           \
            float x_ = (((BYTE) >> (4 + jj)) & 1u) ? e_ : 0.f;                 \
            dsum += x_; wv_[4 + jj] = bf16_rtne(x_);                           \
        }                                                                      \
        *(s8v*)&wt[P][prow * 256 + (((U) ^ (prow & 7)) << 3)] = wv_;           \
    }

    // prologue: full WGEN for chunk 0 -> wt[0] (adj latency exposed once);
    // preload B tiles 0 and 1
    {
#pragma unroll
        for (int k_ = 0; k_ < 4; ++k_) {
            const int u_ = jg + 8 * k_;
            uint32_t mk_;
            GAT_MLOAD(mk_, adjrow, u_)
            float4 fa_ = *(const float4*)(f2base + u_ * 8);
            float4 fb_ = *(const float4*)(f2base + u_ * 8 + 4);
            GAT_WUNIT(u_, mk_, fa_, fb_, 0)
        }
    }
    s8v breg[2][4];
    GAT_BLOAD(breg[0], 0)
    GAT_BLOAD(breg[1], 1)
    __syncthreads();

    int kt = 0;
#pragma unroll 1
    for (int ch = 0; ch < 16; ++ch) {
        const int p = ch & 1;
        const int chn = (ch + 1) & 15;         // next chunk's inputs
        const int* adjn = adjrow + chn * 256;
        const float* f2n = f2base + chn * 256;
        uint32_t mkn_[4];                      // unit k loaded at kk=k (static idx)
        float4 fan_[4], fbn_[4];

#pragma unroll
        for (int kk = 0; kk < 8; ++kk, ++kt) {
            const int e = kk & 1;                // kt&1 == kk&1 (8 kts/chunk)
            // issue B loads for kt+2 (consumed 2 kts later; wraps to dummy)
            s8v bn[4];
            GAT_BLOAD(bn, (kt + 2) & 127)
            // stagger next-chunk mask/f2 loads: unit kk at kk=0..3
            if (kk < 4 && ch < 15) {
                const int u_ = jg + 8 * kk;
                GAT_MLOAD(mkn_[kk], adjn, u_)
                fan_[kk] = *(const float4*)(f2n + u_ * 8);
                fbn_[kk] = *(const float4*)(f2n + u_ * 8 + 4);
            }
            // A-frags from LDS weight tile
            s8v af[4];
#pragma unroll
            for (int i = 0; i < 4; ++i)
                af[i] = *(const s8v*)&wt[p][(i * 16 + m) * 256
                                            + (((kk * 4 + q) ^ (m & 7)) << 3)];
            // 16 MFMAs on current B regs
#pragma unroll
            for (int nt = 0; nt < 4; ++nt)
#pragma unroll
                for (int i = 0; i < 4; ++i)
                    acc[i][nt] = __builtin_amdgcn_mfma_f32_16x16x32_bf16(af[i], breg[e][nt], acc[i][nt], 0, 0, 0);
            // weight piece for next chunk in the MFMA shadow (3-kt load distance)
            if (kk >= 3 && kk <= 6 && ch < 15) {
                const int k_ = kk - 3;
                const int u_ = jg + 8 * k_;
                GAT_WUNIT(u_, mkn_[k_], fan_[k_], fbn_[k_], p ^ 1)
            }
            // rotate B regs
#pragma unroll
            for (int nt = 0; nt < 4; ++nt) breg[e][nt] = bn[nt];
        }
        __syncthreads();
    }
#undef GAT_BLOAD
#undef GAT_MLOAD
#undef GAT_WUNIT

    // ---- partial denominators: reduce over the 8 producer threads per row
    dsum += __shfl_xor(dsum, 1);
    dsum += __shfl_xor(dsum, 2);
    dsum += __shfl_xor(dsum, 4);
    if (jg == 0) denomp[(size_t)js * NR + r0 + prow] = dsum;

    // ---- partial numerators
    float* np = nump + (size_t)js * NR * FD;
#pragma unroll
    for (int i = 0; i < 4; ++i)
#pragma unroll
        for (int nt = 0; nt < 4; ++nt)
#pragma unroll
            for (int r = 0; r < 4; ++r) {
                int row = r0 + i * 16 + q * 4 + r;
                int col = w * 64 + nt * 16 + m;
                np[(size_t)row * FD + col] = acc[i][nt][r];
            }
}

// ---------------- K5: combine j-split partials, softmax divide, ELU --------
__global__ void k_combine(const float* __restrict__ nump,
                          const float* __restrict__ denomp,
                          float* __restrict__ out)
{
    size_t e = ((size_t)blockIdx.x * 256 + threadIdx.x) * 4;
    int row = (int)(e >> 9);
    float4 n0 = *(const float4*)(nump + e);
    float4 n1 = *(const float4*)(nump + (size_t)NR * FD + e);
    float d = denomp[row] + denomp[NR + row];
    float inv = 1.0f / d;
    float4 o;
    o.x = (n0.x + n1.x) * inv;
    o.y = (n0.y + n1.y) * inv;
    o.z = (n0.z + n1.z) * inv;
    o.w = (n0.w + n1.w) * inv;
    o.x = (o.x > 0.f) ? o.x : (__expf(o.x) - 1.f);
    o.y = (o.y > 0.f) ? o.y : (__expf(o.y) - 1.f);
    o.z = (o.z > 0.f) ? o.z : (__expf(o.z) - 1.f);
    o.w = (o.w > 0.f) ? o.w : (__expf(o.w) - 1.f);
    *(float4*)(out + e) = o;
}

extern "C" void kernel_launch(void* const* d_in, const int* in_sizes, int n_in,
                              void* d_out, int out_size, void* d_ws, size_t ws_size,
                              hipStream_t stream) {
    const float* inp = (const float*)d_in[0];
    const int*   adj = (const int*)d_in[1];
    const float* W1  = (const float*)d_in[2];
    const float* b1  = (const float*)d_in[3];
    const float* a1  = (const float*)d_in[4];
    const float* a2  = (const float*)d_in[5];
    const float* b2  = (const float*)d_in[6];
    float* out = (float*)d_out;

    // workspace layout
    short*    inp_bf = (short*)d_ws;                        // 8 MB
    short*    w1t    = inp_bf + (size_t)NR * FD;            // 0.5 MB
    short*    h      = w1t + (size_t)FD * FD;               // 8 MB
    short*    ht3    = h + (size_t)NR * FD;                 // 8 MB
    float*    f1     = (float*)(ht3 + (size_t)FD * NR);     // 32 KB
    float*    f2s    = f1 + NR;                             // 32 KB
    float*    nump   = f2s + NR;                            // 32 MB
    float*    denomp = nump + (size_t)2 * NR * FD;          // 64 KB

    k_prep<<<4096 + 1024, 256, 0, stream>>>(inp, inp_bf, W1, w1t);
    dim3 g1(NR / 32, FD / 128);
    k_gemm_h<<<g1, 256, 0, stream>>>(inp_bf, w1t, b1, h, ht3);
    k_f1f2<<<NR / 4, 256, 0, stream>>>(h, a1, a2, b2, f1, f2s);
    k_attn<<<128 * 2, 512, 0, stream>>>(adj, ht3, f1, f2s, nump, denomp);
    k_combine<<<(NR * FD / 4) / 256, 256, 0, stream>>>(nump, denomp, out);
}

// Round 3
// 459.729 us; speedup vs baseline: 1.0575x; 1.0575x over previous
//
#include <hip/hip_runtime.h>
#include <hip/hip_bf16.h>
#include <stdint.h>

#define NR 8192
#define FD 512
#define BM 64     // k_attn rows per band

typedef __attribute__((ext_vector_type(8))) short s8v;   // 8 bf16 (4 VGPRs) - MFMA A/B frag
typedef __attribute__((ext_vector_type(4))) float f32x4; // MFMA C/D frag

static __device__ __forceinline__ short bf16_rtne(float x) {
    union { float f; uint32_t u; } v; v.f = x;
    uint32_t r = (v.u + 0x7FFFu + ((v.u >> 16) & 1u)) >> 16;
    return (short)r;
}
static __device__ __forceinline__ float bf16_to_f32(short s) {
    union { uint32_t u; float f; } v; v.u = ((uint32_t)(uint16_t)s) << 16;
    return v.f;
}

// ---------------- K0: fused fp32->bf16 convert (inp) + W1 transpose --------
__global__ void k_prep(const float* __restrict__ in, short* __restrict__ out,
                       const float* __restrict__ W1, short* __restrict__ W1T) {
    int b = blockIdx.x;
    if (b < 4096) {
        int i = b * 256 + threadIdx.x;               // one float4 per thread
        float4 v = ((const float4*)in)[i];
        short4 s;
        s.x = bf16_rtne(v.x); s.y = bf16_rtne(v.y);
        s.z = bf16_rtne(v.z); s.w = bf16_rtne(v.w);
        ((short4*)out)[i] = s;
    } else {
        int i = (b - 4096) * 256 + threadIdx.x;      // 512*512
        int k = i & 511, n = i >> 9;
        W1T[(size_t)n * 512 + k] = bf16_rtne(W1[(size_t)k * 512 + n]);
    }
}

// ---------------- K1: h = inp @ W1 + b1 ; writes h AND ht3 ----------------
// ht3 layout per 32-j tile jt: [wave=c/64][nt=(c%64)/16][qg=jrow/8][cm=c%16][jr=jrow%8]
// -> every k_attn B-frag load is a fully-coalesced lane-linear 1KB dwordx4.
__launch_bounds__(256)
__global__ void k_gemm_h(const short* __restrict__ A,   // inp bf16 [8192][512]
                         const short* __restrict__ BT,  // W1T bf16 [512][512]
                         const float* __restrict__ b1,
                         short* __restrict__ H,         // bf16 [8192][512]
                         short* __restrict__ HT3)       // bf16 [256][16384]
{
    const int lane = threadIdx.x & 63;
    const int wn   = threadIdx.x >> 6;     // 0..3
    const int m    = lane & 15;
    const int q    = lane >> 4;
    const int r0   = blockIdx.x * 32;
    const int c0   = blockIdx.y * 128 + wn * 32;

    f32x4 acc[2][2] = {};
#pragma unroll 1
    for (int k0 = 0; k0 < 512; k0 += 32) {
        s8v a[2], b[2];
#pragma unroll
        for (int rt = 0; rt < 2; ++rt)
            a[rt] = *(const s8v*)(A + (size_t)(r0 + rt * 16 + m) * 512 + k0 + q * 8);
#pragma unroll
        for (int nt = 0; nt < 2; ++nt)
            b[nt] = *(const s8v*)(BT + (size_t)(c0 + nt * 16 + m) * 512 + k0 + q * 8);
#pragma unroll
        for (int rt = 0; rt < 2; ++rt)
#pragma unroll
            for (int nt = 0; nt < 2; ++nt)
                acc[rt][nt] = __builtin_amdgcn_mfma_f32_16x16x32_bf16(a[rt], b[nt], acc[rt][nt], 0, 0, 0);
    }
    float b1v[2];
#pragma unroll
    for (int nt = 0; nt < 2; ++nt) b1v[nt] = b1[c0 + nt * 16 + m];

#pragma unroll
    for (int rt = 0; rt < 2; ++rt)
#pragma unroll
        for (int nt = 0; nt < 2; ++nt) {
            int col = c0 + nt * 16 + m;
            short4 hp;
#pragma unroll
            for (int r = 0; r < 4; ++r) {
                int row = r0 + rt * 16 + q * 4 + r;
                short hv = bf16_rtne(acc[rt][nt][r] + b1v[nt]);
                H[(size_t)row * 512 + col] = hv;
                ((short*)&hp)[r] = hv;
            }
            size_t off = (size_t)blockIdx.x * 16384
                       + (size_t)(blockIdx.y * 2 + (wn >> 1)) * 2048
                       + (size_t)((wn * 2 + nt) & 3) * 512
                       + (rt * 2 + (q >> 1)) * 128
                       + m * 8 + (q & 1) * 4;
            *(short4*)(HT3 + off) = hp;
        }
}

// ---------------- K3: f1 = h@a1, f2s = h@a2 + b2 ----------------
__global__ void k_f1f2(const short* __restrict__ H, const float* __restrict__ a1,
                       const float* __restrict__ a2, const float* __restrict__ b2,
                       float* __restrict__ f1, float* __restrict__ f2s)
{
    const int lane = threadIdx.x & 63;
    const int row  = blockIdx.x * 4 + (threadIdx.x >> 6);
    s8v hv = *(const s8v*)(H + (size_t)row * 512 + lane * 8);
    float4 a1l = ((const float4*)(a1 + lane * 8))[0];
    float4 a1h = ((const float4*)(a1 + lane * 8))[1];
    float4 a2l = ((const float4*)(a2 + lane * 8))[0];
    float4 a2h = ((const float4*)(a2 + lane * 8))[1];
    float hf[8];
#pragma unroll
    for (int i = 0; i < 8; ++i) hf[i] = bf16_to_f32(hv[i]);
    float s1 = hf[0] * a1l.x + hf[1] * a1l.y + hf[2] * a1l.z + hf[3] * a1l.w
             + hf[4] * a1h.x + hf[5] * a1h.y + hf[6] * a1h.z + hf[7] * a1h.w;
    float s2 = hf[0] * a2l.x + hf[1] * a2l.y + hf[2] * a2l.z + hf[3] * a2l.w
             + hf[4] * a2h.x + hf[5] * a2h.y + hf[6] * a2h.z + hf[7] * a2h.w;
#pragma unroll
    for (int o = 32; o > 0; o >>= 1) {
        s1 += __shfl_xor(s1, o);
        s2 += __shfl_xor(s2, o);
    }
    if (lane == 0) {
        f1[row]  = s1;
        f2s[row] = s2 + b2[0];
    }
}

// ---------------- K4: fused masked-softmax attention @ h (partials) --------
// grid 256 = 128 bands x 2 j-splits, 1024 thr / 16 waves (4 waves/SIMD).
// Same tile and traffic as before, but each wave owns 32 output cols
// (acc [4][2] = 32 VGPR) so the whole wave state fits the 128-VGPR budget
// required for 4 waves/SIMD -> double the latency hiding of the old
// 512-thread version. adj is read directly and compressed to a per-unit
// byte mask at load time (kk=0..1, MFMA shadow); consumed at kk=4..5
// (~2000 cyc distance -> covers HBM latency). B-frags: depth-2 register
// prefetch from ht3 (coalesced 1KB dwordx4). Weight tile: LDS dbuf (64 KB),
// one barrier per 256-j chunk.
__launch_bounds__(1024, 4)
__global__ void k_attn(const int* __restrict__ adj,    // [8192][8192] int 0/1
                       const short* __restrict__ HT3,  // [256][16384]
                       const float* __restrict__ f1,
                       const float* __restrict__ f2s,
                       float* __restrict__ nump,       // [2][8192][512]
                       float* __restrict__ denomp)     // [2][8192]
{
    __shared__ __align__(16) short wt[2][BM * 256];    // 2 x 32 KB

    const int t    = threadIdx.x;
    const int lane = t & 63;
    const int w    = t >> 6;          // 0..15 col group (32 cols)
    const int m    = lane & 15;
    const int q    = lane >> 4;

    const int js   = blockIdx.x & 1;
    const int band = blockIdx.x >> 1; // 0..127
    const int r0   = band * BM;
    const int jb0  = js * 4096;
    const int jt0  = js * 128;        // first 32-j tile index

    const int prow = t >> 4;          // 0..63
    const int jg   = t & 15;          // 0..15 (16 producers per row)

    const float f1v = f1[r0 + prow];
    const int* adjrow = adj + (size_t)(r0 + prow) * NR + jb0;
    const float* f2base = f2s + jb0;

    f32x4 acc[4][2] = {};
    float dsum = 0.f;

#define GAT_BLOAD(DST, KT)                                                     \
    {                                                                          \
        const short* s_ = HT3 + (size_t)(jt0 + (KT)) * 16384 + (w >> 1) * 2048 \
                        + (w & 1) * 1024 + q * 128 + m * 8;                    \
        DST[0] = *(const s8v*)(s_);                                            \
        DST[1] = *(const s8v*)(s_ + 512);                                      \
    }

// load 8 adj ints for unit U and compress to an 8-bit mask (bit jj = col jj)
#define GAT_MLOAD(DST, AP, U)                                                  \
    {                                                                          \
        uint4 ma_ = *(const uint4*)((AP) + (U) * 8);                           \
        uint4 mb_ = *(const uint4*)((AP) + (U) * 8 + 4);                       \
        DST = ((int)ma_.x > 0 ? 1u : 0u)  | ((int)ma_.y > 0 ? 2u : 0u)         \
            | ((int)ma_.z > 0 ? 4u : 0u)  | ((int)ma_.w > 0 ? 8u : 0u)         \
            | ((int)mb_.x > 0 ? 16u : 0u) | ((int)mb_.y > 0 ? 32u : 0u)        \
            | ((int)mb_.z > 0 ? 64u : 0u) | ((int)mb_.w > 0 ? 128u : 0u);      \
    }

// one unit (8 weights) of row prow into wt[P]; BYTE = 8-bit mask, FA/FB float4
#define GAT_WUNIT(U, BYTE, FA, FB, P)                                          \
    {                                                                          \
        s8v wv_;                                                               \
        const float* ff_ = (const float*)&(FA);                                \
        _Pragma("unroll")                                                      \
        for (int jj = 0; jj < 4; ++jj) {                                       \
            float s_ = f1v + ff_[jj];                                          \
            float e_ = __expf(fmaxf(s_, 0.2f * s_));                           \
            float x_ = (((BYTE) >> jj) & 1u) ? e_ : 0.f;                       \
            dsum += x_; wv_[jj] = bf16_rtne(x_);                               \
        }                                                                      \
        const float* fg_ = (const float*)&(FB);                               \
        _Pragma("unroll")                                                      \
        for (int jj = 0; jj < 4; ++jj) {                                       \
            float s_ = f1v + fg_[jj];                                          \
            float e_ = __expf(fmaxf(s_, 0.2f * s_));                           \
            float x_ = (((BYTE) >> (4 + jj)) & 1u) ? e_ : 0.f;                 \
            dsum += x_; wv_[4 + jj] = bf16_rtne(x_);                           \
        }                                                                      \
        *(s8v*)&wt[P][prow * 256 + (((U) ^ (prow & 7)) << 3)] = wv_;           \
    }

    // prologue: full WGEN for chunk 0 -> wt[0] (adj latency exposed once);
    // preload B tiles 0 and 1
    {
#pragma unroll
        for (int k_ = 0; k_ < 2; ++k_) {
            const int u_ = jg + 16 * k_;
            uint32_t mk_;
            GAT_MLOAD(mk_, adjrow, u_)
            float4 fa_ = *(const float4*)(f2base + u_ * 8);
            float4 fb_ = *(const float4*)(f2base + u_ * 8 + 4);
            GAT_WUNIT(u_, mk_, fa_, fb_, 0)
        }
    }
    s8v breg[2][2];
    GAT_BLOAD(breg[0], 0)
    GAT_BLOAD(breg[1], 1)
    __syncthreads();

    int kt = 0;
#pragma unroll 1
    for (int ch = 0; ch < 16; ++ch) {
        const int p = ch & 1;
        const int chn = (ch + 1) & 15;         // next chunk's inputs
        const int* adjn = adjrow + chn * 256;
        const float* f2n = f2base + chn * 256;
        uint32_t mkn_[2];                      // unit k loaded at kk=k (static idx)
        float4 fan_[2], fbn_[2];

#pragma unroll
        for (int kk = 0; kk < 8; ++kk, ++kt) {
            const int e = kk & 1;                // kt&1 == kk&1 (8 kts/chunk)
            // issue B loads for kt+2 (consumed 2 kts later; wraps to dummy)
            s8v bn[2];
            GAT_BLOAD(bn, (kt + 2) & 127)
            // stagger next-chunk mask/f2 loads: unit kk at kk=0..1
            if (kk < 2 && ch < 15) {
                const int u_ = jg + 16 * kk;
                GAT_MLOAD(mkn_[kk], adjn, u_)
                fan_[kk] = *(const float4*)(f2n + u_ * 8);
                fbn_[kk] = *(const float4*)(f2n + u_ * 8 + 4);
            }
            // A-frags from LDS weight tile
            s8v af[4];
#pragma unroll
            for (int i = 0; i < 4; ++i)
                af[i] = *(const s8v*)&wt[p][(i * 16 + m) * 256
                                            + (((kk * 4 + q) ^ (m & 7)) << 3)];
            // 8 MFMAs on current B regs
#pragma unroll
            for (int nt = 0; nt < 2; ++nt)
#pragma unroll
                for (int i = 0; i < 4; ++i)
                    acc[i][nt] = __builtin_amdgcn_mfma_f32_16x16x32_bf16(af[i], breg[e][nt], acc[i][nt], 0, 0, 0);
            // weight piece for next chunk in the MFMA shadow (4-kt load distance)
            if (kk >= 4 && kk <= 5 && ch < 15) {
                const int k_ = kk - 4;
                const int u_ = jg + 16 * k_;
                GAT_WUNIT(u_, mkn_[k_], fan_[k_], fbn_[k_], p ^ 1)
            }
            // rotate B regs
#pragma unroll
            for (int nt = 0; nt < 2; ++nt) breg[e][nt] = bn[nt];
        }
        __syncthreads();
    }
#undef GAT_BLOAD
#undef GAT_MLOAD
#undef GAT_WUNIT

    // ---- partial denominators: reduce over the 16 producer threads per row
    dsum += __shfl_xor(dsum, 1);
    dsum += __shfl_xor(dsum, 2);
    dsum += __shfl_xor(dsum, 4);
    dsum += __shfl_xor(dsum, 8);
    if (jg == 0) denomp[(size_t)js * NR + r0 + prow] = dsum;

    // ---- partial numerators
    float* np = nump + (size_t)js * NR * FD;
#pragma unroll
    for (int i = 0; i < 4; ++i)
#pragma unroll
        for (int nt = 0; nt < 2; ++nt)
#pragma unroll
            for (int r = 0; r < 4; ++r) {
                int row = r0 + i * 16 + q * 4 + r;
                int col = w * 32 + nt * 16 + m;
                np[(size_t)row * FD + col] = acc[i][nt][r];
            }
}

// ---------------- K5: combine j-split partials, softmax divide, ELU --------
__global__ void k_combine(const float* __restrict__ nump,
                          const float* __restrict__ denomp,
                          float* __restrict__ out)
{
    size_t e = ((size_t)blockIdx.x * 256 + threadIdx.x) * 4;
    int row = (int)(e >> 9);
    float4 n0 = *(const float4*)(nump + e);
    float4 n1 = *(const float4*)(nump + (size_t)NR * FD + e);
    float d = denomp[row] + denomp[NR + row];
    float inv = 1.0f / d;
    float4 o;
    o.x = (n0.x + n1.x) * inv;
    o.y = (n0.y + n1.y) * inv;
    o.z = (n0.z + n1.z) * inv;
    o.w = (n0.w + n1.w) * inv;
    o.x = (o.x > 0.f) ? o.x : (__expf(o.x) - 1.f);
    o.y = (o.y > 0.f) ? o.y : (__expf(o.y) - 1.f);
    o.z = (o.z > 0.f) ? o.z : (__expf(o.z) - 1.f);
    o.w = (o.w > 0.f) ? o.w : (__expf(o.w) - 1.f);
    *(float4*)(out + e) = o;
}

extern "C" void kernel_launch(void* const* d_in, const int* in_sizes, int n_in,
                              void* d_out, int out_size, void* d_ws, size_t ws_size,
                              hipStream_t stream) {
    const float* inp = (const float*)d_in[0];
    const int*   adj = (const int*)d_in[1];
    const float* W1  = (const float*)d_in[2];
    const float* b1  = (const float*)d_in[3];
    const float* a1  = (const float*)d_in[4];
    const float* a2  = (const float*)d_in[5];
    const float* b2  = (const float*)d_in[6];
    float* out = (float*)d_out;

    // workspace layout
    short*    inp_bf = (short*)d_ws;                        // 8 MB
    short*    w1t    = inp_bf + (size_t)NR * FD;            // 0.5 MB
    short*    h      = w1t + (size_t)FD * FD;               // 8 MB
    short*    ht3    = h + (size_t)NR * FD;                 // 8 MB
    float*    f1     = (float*)(ht3 + (size_t)FD * NR);     // 32 KB
    float*    f2s    = f1 + NR;                             // 32 KB
    float*    nump   = f2s + NR;                            // 32 MB
    float*    denomp = nump + (size_t)2 * NR * FD;          // 64 KB

    k_prep<<<4096 + 1024, 256, 0, stream>>>(inp, inp_bf, W1, w1t);
    dim3 g1(NR / 32, FD / 128);
    k_gemm_h<<<g1, 256, 0, stream>>>(inp_bf, w1t, b1, h, ht3);
    k_f1f2<<<NR / 4, 256, 0, stream>>>(h, a1, a2, b2, f1, f2s);
    k_attn<<<128 * 2, 1024, 0, stream>>>(adj, ht3, f1, f2s, nump, denomp);
    k_combine<<<(NR * FD / 4) / 256, 256, 0, stream>>>(nump, denomp, out);
}